// Round 3
// baseline (720.618 us; speedup 1.0000x reference)
//
#include <hip/hip_runtime.h>
#include <hip/hip_bf16.h>

typedef __bf16 bf16;
typedef __bf16 bf16x4 __attribute__((ext_vector_type(4)));
typedef __bf16 bf16x8 __attribute__((ext_vector_type(8)));
typedef float  f32x4  __attribute__((ext_vector_type(4)));

#define F_IN  128
#define C_MID 64
#define BN_EPSF 1e-5f

// ws layout (floats):
//  [0..63]   sum rawG   [64..127]  sum rawG^2
//  [128..191] sum rawX  [192..255] sum rawX^2
//  [256],[257] sum s, sum s^2
//  [512...]  s array (N floats)
// gx scratch = d_out (256 MB bf16, dead until final pass):
//  group g: G block 2048 B at g*4096, X block at g*4096+2048.
//  In-block: lane*32 B = [cb0 j0..3][cb1] | +16B: [cb2][cb3],
//  value = point (g*16 + quad*4 + j), channel (cb*16 + row16).

// PHASE 0: per-matrix-specialized blocks. Contiguous loads (2 groups deep),
// per-wave swizzled LDS transpose, MFMA vs LDS weights, raw stats, bf16 store.
__global__ __launch_bounds__(256, 4) void k_p0(
    const float* __restrict__ gate, const float* __restrict__ skip,
    const float* __restrict__ Wg,   const float* __restrict__ Wx,
    float* __restrict__ stats, bf16* __restrict__ gx, int ngroups)
{
  __shared__ bf16x8 wfrag[4][4][64];             // 16 KiB (one matrix)
  __shared__ __align__(16) bf16 atile[4][2048];  // 16 KiB (per-wave 16x128 tiles)
  __shared__ float  red[128];

  const int tid = threadIdx.x;
  const int mat = blockIdx.x & 1;
  const float* W   = mat ? Wx   : Wg;
  const float* src = mat ? skip : gate;

  // stage weights (fragment order: col=ln&15 -> channel, k=(ln>>4)*8+j)
  for (int e = tid; e < 1024; e += 256) {
    const int cb = e >> 8, kc = (e >> 6) & 3, ln = e & 63;
    const int c  = cb*16 + (ln & 15);
    const int k0 = kc*32 + (ln >> 4)*8;
    bf16x8 t;
#pragma unroll
    for (int j = 0; j < 8; ++j) t[j] = (bf16)W[(k0 + j)*C_MID + c];
    wfrag[cb][kc][ln] = t;
  }
  if (tid < 128) red[tid] = 0.f;
  __syncthreads();

  const int lane = tid & 63, wid = tid >> 6;
  const int row16 = lane & 15, quad = lane >> 4;
  bf16* at = atile[wid];
  float s1[4] = {0,0,0,0}, s2[4] = {0,0,0,0};

  const int s0 = (blockIdx.x >> 1)*4 + wid;   // stream id, [0, 4096)
  const int ns = (gridDim.x >> 1)*4;          // 4096 streams per matrix

#define PROCESS(L, g)                                                          \
  {                                                                            \
    _Pragma("unroll")                                                          \
    for (int i = 0; i < 8; ++i) {                                              \
      const int r = i*2 + (lane >> 5);                                         \
      const int cbyte = ((lane & 31)*8) ^ ((r & 7) << 4);                      \
      bf16x4 t;                                                                \
      _Pragma("unroll")                                                        \
      for (int j = 0; j < 4; ++j) t[j] = (bf16)L[i][j];                        \
      *(bf16x4*)((char*)at + r*256 + cbyte) = t;                               \
    }                                                                          \
    bf16x8 af[4];                                                              \
    _Pragma("unroll")                                                          \
    for (int kc = 0; kc < 4; ++kc) {                                           \
      const int cbyte = (kc*64 + quad*16) ^ ((row16 & 7) << 4);                \
      af[kc] = *(const bf16x8*)((const char*)at + row16*256 + cbyte);          \
    }                                                                          \
    f32x4 acc[4];                                                              \
    _Pragma("unroll")                                                          \
    for (int cb = 0; cb < 4; ++cb) acc[cb] = f32x4{0.f,0.f,0.f,0.f};           \
    _Pragma("unroll")                                                          \
    for (int cb = 0; cb < 4; ++cb)                                             \
      _Pragma("unroll")                                                        \
      for (int kc = 0; kc < 4; ++kc)                                           \
        acc[cb] = __builtin_amdgcn_mfma_f32_16x16x32_bf16(                     \
            af[kc], wfrag[cb][kc][lane], acc[cb], 0, 0, 0);                    \
    bf16x8 o0, o1;                                                             \
    _Pragma("unroll")                                                          \
    for (int cb = 0; cb < 4; ++cb) {                                           \
      _Pragma("unroll")                                                        \
      for (int j = 0; j < 4; ++j) {                                            \
        const float v = acc[cb][j];                                            \
        s1[cb] += v; s2[cb] += v*v;                                            \
        if (cb < 2) o0[cb*4 + j] = (bf16)v; else o1[(cb-2)*4 + j] = (bf16)v;   \
      }                                                                        \
    }                                                                          \
    char* dst = (char*)gx + ((size_t)(g)*2 + mat)*2048 + lane*32;              \
    *(bf16x8*)dst        = o0;                                                 \
    *(bf16x8*)(dst + 16) = o1;                                                 \
  }

  for (int p = s0; 2*p < ngroups; p += ns) {
    const int g0 = 2*p, g1 = g0 + 1;
    const float* pa = src + (size_t)g0 * 2048;
    f32x4 La[8], Lb[8];
#pragma unroll
    for (int i = 0; i < 8; ++i) La[i] = *(const f32x4*)(pa + i*256 + lane*4);
    const bool has2 = (g1 < ngroups);
    if (has2) {
      const float* pb = src + (size_t)g1 * 2048;
#pragma unroll
      for (int i = 0; i < 8; ++i) Lb[i] = *(const f32x4*)(pb + i*256 + lane*4);
    }
    PROCESS(La, g0)
    if (has2) PROCESS(Lb, g1)
  }
#undef PROCESS

  // quad-reduce then per-channel block/global reduce
#pragma unroll
  for (int cb = 0; cb < 4; ++cb) {
    s1[cb] += __shfl_xor(s1[cb], 16, 64);  s1[cb] += __shfl_xor(s1[cb], 32, 64);
    s2[cb] += __shfl_xor(s2[cb], 16, 64);  s2[cb] += __shfl_xor(s2[cb], 32, 64);
  }
  if (lane < 16) {
#pragma unroll
    for (int cb = 0; cb < 4; ++cb) {
      const int c = cb*16 + lane;
      atomicAdd(&red[c],      s1[cb]);
      atomicAdd(&red[64 + c], s2[cb]);
    }
  }
  __syncthreads();
  if (tid < 128) atomicAdd(&stats[mat*128 + tid], red[tid]);
}

// PHASE 1: read G,X bf16, fold BN (biases cancel in BN), s = relu(z)@Wpsi,
// store s (fp32) + scalar s stats.
__global__ __launch_bounds__(256) void k_p1(
    const bf16* __restrict__ gx, const float* __restrict__ stats,
    const float* __restrict__ gamma_g, const float* __restrict__ beta_g,
    const float* __restrict__ gamma_x, const float* __restrict__ beta_x,
    const float* __restrict__ Wpsi,
    float* __restrict__ sArr, float* __restrict__ sstat,
    int ngroups, float inv_n)
{
  __shared__ float pAg[64], pAx[64], pK[64], pW[64];
  const int tid = threadIdx.x;
  if (tid < 64) {
    const float mG = stats[tid]*inv_n,       vG = stats[64 + tid]*inv_n  - mG*mG;
    const float mX = stats[128 + tid]*inv_n, vX = stats[192 + tid]*inv_n - mX*mX;
    const float Ag = gamma_g[tid] * rsqrtf(vG + BN_EPSF);
    const float Ax = gamma_x[tid] * rsqrtf(vX + BN_EPSF);
    pAg[tid] = Ag; pAx[tid] = Ax;
    pK[tid]  = beta_g[tid] - mG*Ag + beta_x[tid] - mX*Ax;
    pW[tid]  = Wpsi[tid];
  }
  __syncthreads();

  const int lane = tid & 63, wid = tid >> 6;
  const int row16 = lane & 15, quad = lane >> 4;
  float Ag[4], Ax[4], K[4], W[4];
#pragma unroll
  for (int cb = 0; cb < 4; ++cb) {
    const int c = cb*16 + row16;
    Ag[cb] = pAg[c]; Ax[cb] = pAx[c]; K[cb] = pK[c]; W[cb] = pW[c];
  }

  float aS = 0.f, aS2 = 0.f;
  const int g0 = blockIdx.x*4 + wid, ng = gridDim.x*4;
  for (int g = g0; g < ngroups; g += ng) {
    const char* base = (const char*)gx + (size_t)g*4096 + lane*32;
    const bf16x8 gA = *(const bf16x8*)(base);
    const bf16x8 gB = *(const bf16x8*)(base + 16);
    const bf16x8 xA = *(const bf16x8*)(base + 2048);
    const bf16x8 xB = *(const bf16x8*)(base + 2048 + 16);
    float ps[4] = {0,0,0,0};
#pragma unroll
    for (int cb = 0; cb < 4; ++cb) {
#pragma unroll
      for (int j = 0; j < 4; ++j) {
        const float gv = (float)(cb < 2 ? gA[cb*4 + j] : gB[(cb-2)*4 + j]);
        const float xv = (float)(cb < 2 ? xA[cb*4 + j] : xB[(cb-2)*4 + j]);
        float z = fmaf(gv, Ag[cb], fmaf(xv, Ax[cb], K[cb]));
        z = fmaxf(z, 0.f);
        ps[j] = fmaf(z, W[cb], ps[j]);
      }
    }
#pragma unroll
    for (int j = 0; j < 4; ++j) {
      ps[j] += __shfl_xor(ps[j], 1, 64);
      ps[j] += __shfl_xor(ps[j], 2, 64);
      ps[j] += __shfl_xor(ps[j], 4, 64);
      ps[j] += __shfl_xor(ps[j], 8, 64);
    }
    if (row16 == 0) {
#pragma unroll
      for (int j = 0; j < 4; ++j) {
        const float sv = ps[j];
        sArr[g*16 + quad*4 + j] = sv;
        aS += sv; aS2 += sv*sv;
      }
    }
  }
  aS  += __shfl_xor(aS, 16, 64);  aS  += __shfl_xor(aS, 32, 64);
  aS2 += __shfl_xor(aS2,16, 64);  aS2 += __shfl_xor(aS2,32, 64);
  if (lane == 0) { atomicAdd(&sstat[0], aS); atomicAdd(&sstat[1], aS2); }
}

// PHASE 2: out = skip * sigmoid(BN(s))  (bpsi cancels in BN)
__global__ void k_out(const float* __restrict__ skip,
                      const float* __restrict__ sArr,
                      const float* __restrict__ sstat,
                      const float* __restrict__ gamma_psi,
                      const float* __restrict__ beta_psi,
                      float* __restrict__ out, int N)
{
  const float inv_n = 1.0f / (float)N;
  const float m = sstat[0] * inv_n;
  const float v = sstat[1] * inv_n - m*m;
  const float A = gamma_psi[0] * rsqrtf(v + BN_EPSF);
  const float B = beta_psi[0] - m*A;
  const long total  = (long)N * (F_IN/4);
  const long stride = (long)gridDim.x * blockDim.x;
  for (long i = (long)blockIdx.x*blockDim.x + threadIdx.x; i < total; i += stride) {
    const int p = (int)(i >> 5);        // 32 f32x4 per point
    const float t = sArr[p]*A + B;
    const float psi = 1.0f / (1.0f + __expf(-t));
    f32x4 vv = ((const f32x4*)skip)[i];
    ((f32x4*)out)[i] = vv * psi;
  }
}

extern "C" void kernel_launch(void* const* d_in, const int* in_sizes, int n_in,
                              void* d_out, int out_size, void* d_ws, size_t ws_size,
                              hipStream_t stream)
{
  const float* gate      = (const float*)d_in[0];
  const float* skip      = (const float*)d_in[1];
  const float* Wg        = (const float*)d_in[2];
  const float* gamma_g   = (const float*)d_in[4];
  const float* beta_g    = (const float*)d_in[5];
  const float* Wx        = (const float*)d_in[6];
  const float* gamma_x   = (const float*)d_in[8];
  const float* beta_x    = (const float*)d_in[9];
  const float* Wpsi      = (const float*)d_in[10];
  const float* gamma_psi = (const float*)d_in[12];
  const float* beta_psi  = (const float*)d_in[13];

  float* ws   = (float*)d_ws;
  float* sArr = ws + 512;
  bf16*  gx   = (bf16*)d_out;      // d_out (512 MB) doubles as 256 MB scratch
  float* out  = (float*)d_out;

  const int N = in_sizes[0] / F_IN;
  const int ngroups = N / 16;

  hipMemsetAsync(d_ws, 0, 512*sizeof(float), stream);

  k_p0<<<dim3(2048), dim3(256), 0, stream>>>(gate, skip, Wg, Wx, ws, gx, ngroups);
  k_p1<<<dim3(2048), dim3(256), 0, stream>>>(gx, ws, gamma_g, beta_g, gamma_x, beta_x,
                                             Wpsi, sArr, ws + 256, ngroups, 1.0f/(float)N);
  k_out<<<dim3(2048), dim3(256), 0, stream>>>(skip, sArr, ws + 256, gamma_psi, beta_psi, out, N);
}

// Round 4
// 697.521 us; speedup vs baseline: 1.0331x; 1.0331x over previous
//
#include <hip/hip_runtime.h>
#include <hip/hip_bf16.h>

typedef __bf16 bf16;
typedef __bf16 bf16x4 __attribute__((ext_vector_type(4)));
typedef __bf16 bf16x8 __attribute__((ext_vector_type(8)));
typedef float  f32x4  __attribute__((ext_vector_type(4)));

#define F_IN  128
#define C_MID 64
#define BN_EPSF 1e-5f

// ws layout:
//  floats [0..63] sum rawG, [64..127] sum rawG^2, [128..191] sum rawX,
//         [192..255] sum rawX^2, [256],[257] sum s, sum s^2
//  floats [512...] s array (N floats)
//  byte offset 32 MB: gx scratch (256 MB bf16)  [falls back to d_out if ws small]
// gx layout: group g: G block 2048 B at g*4096, X block at +2048.
//  In-block: lane*32 B = [cb0 j0..3][cb1] | +16B: [cb2][cb3],
//  value = point (g*16 + quad*4 + j), channel (cb*16 + row16).

// PHASE 0: 512-thread blocks, one matrix per block. Contiguous 1-KB wave
// loads, per-wave swizzled LDS transpose, MFMA vs LDS weights, raw stats,
// bf16 store of G or X.
__global__ __launch_bounds__(512, 4) void k_p0(
    const float* __restrict__ gate, const float* __restrict__ skip,
    const float* __restrict__ Wg,   const float* __restrict__ Wx,
    float* __restrict__ stats, bf16* __restrict__ gx, int ngroups)
{
  __shared__ bf16x8 wfrag[4][4][64];             // 16 KiB (one matrix)
  __shared__ __align__(16) bf16 atile[8][2048];  // 32 KiB (per-wave 16x128 tiles)
  __shared__ float  red[128];

  const int tid = threadIdx.x;
  const int mat = blockIdx.x & 1;
  const float* W   = mat ? Wx   : Wg;
  const float* src = mat ? skip : gate;

  // stage weights (fragment order: col=ln&15 -> channel, k=(ln>>4)*8+j)
  for (int e = tid; e < 1024; e += 512) {
    const int cb = e >> 8, kc = (e >> 6) & 3, ln = e & 63;
    const int c  = cb*16 + (ln & 15);
    const int k0 = kc*32 + (ln >> 4)*8;
    bf16x8 t;
#pragma unroll
    for (int j = 0; j < 8; ++j) t[j] = (bf16)W[(k0 + j)*C_MID + c];
    wfrag[cb][kc][ln] = t;
  }
  if (tid < 128) red[tid] = 0.f;
  __syncthreads();

  const int lane = tid & 63, wid = tid >> 6;
  const int row16 = lane & 15, quad = lane >> 4;
  bf16* at = atile[wid];
  float s1[4] = {0,0,0,0}, s2[4] = {0,0,0,0};

  const int s0 = (blockIdx.x >> 1)*8 + wid;   // stream id within this matrix
  const int ns = (gridDim.x >> 1)*8;

  for (int g = s0; g < ngroups; g += ns) {
    const float* p = src + (size_t)g * 2048;
    // 8 contiguous 1-KB wave loads (lane-linear)
    f32x4 L[8];
#pragma unroll
    for (int i = 0; i < 8; ++i) L[i] = *(const f32x4*)(p + i*256 + lane*4);
    // cvt -> bf16, swizzled ds_write (byte ^= (row&7)<<4)
#pragma unroll
    for (int i = 0; i < 8; ++i) {
      const int r = i*2 + (lane >> 5);
      const int cbyte = ((lane & 31)*8) ^ ((r & 7) << 4);
      bf16x4 t;
#pragma unroll
      for (int j = 0; j < 4; ++j) t[j] = (bf16)L[i][j];
      *(bf16x4*)((char*)at + r*256 + cbyte) = t;
    }
    // fragment reads (same swizzle)
    bf16x8 af[4];
#pragma unroll
    for (int kc = 0; kc < 4; ++kc) {
      const int cbyte = (kc*64 + quad*16) ^ ((row16 & 7) << 4);
      af[kc] = *(const bf16x8*)((const char*)at + row16*256 + cbyte);
    }
    f32x4 acc[4];
#pragma unroll
    for (int cb = 0; cb < 4; ++cb) acc[cb] = f32x4{0.f,0.f,0.f,0.f};
#pragma unroll
    for (int cb = 0; cb < 4; ++cb)
#pragma unroll
      for (int kc = 0; kc < 4; ++kc)
        acc[cb] = __builtin_amdgcn_mfma_f32_16x16x32_bf16(af[kc], wfrag[cb][kc][lane], acc[cb], 0, 0, 0);

    // stats on raw values + pack + contiguous bf16 store
    bf16x8 o0, o1;
#pragma unroll
    for (int cb = 0; cb < 4; ++cb) {
#pragma unroll
      for (int j = 0; j < 4; ++j) {
        const float v = acc[cb][j];
        s1[cb] += v; s2[cb] += v*v;
        if (cb < 2) o0[cb*4 + j] = (bf16)v; else o1[(cb-2)*4 + j] = (bf16)v;
      }
    }
    char* dst = (char*)gx + ((size_t)g*2 + mat)*2048 + lane*32;
    *(bf16x8*)dst        = o0;
    *(bf16x8*)(dst + 16) = o1;
  }

  // quad-reduce then per-channel block/global reduce
#pragma unroll
  for (int cb = 0; cb < 4; ++cb) {
    s1[cb] += __shfl_xor(s1[cb], 16, 64);  s1[cb] += __shfl_xor(s1[cb], 32, 64);
    s2[cb] += __shfl_xor(s2[cb], 16, 64);  s2[cb] += __shfl_xor(s2[cb], 32, 64);
  }
  if (lane < 16) {
#pragma unroll
    for (int cb = 0; cb < 4; ++cb) {
      const int c = cb*16 + lane;
      atomicAdd(&red[c],      s1[cb]);
      atomicAdd(&red[64 + c], s2[cb]);
    }
  }
  __syncthreads();
  if (tid < 128) atomicAdd(&stats[mat*128 + tid], red[tid]);
}

// PHASE 1: read G,X bf16, fold BN (biases cancel in BN), s = relu(z)@Wpsi,
// store s (fp32) + scalar s stats.
__global__ __launch_bounds__(256) void k_p1(
    const bf16* __restrict__ gx, const float* __restrict__ stats,
    const float* __restrict__ gamma_g, const float* __restrict__ beta_g,
    const float* __restrict__ gamma_x, const float* __restrict__ beta_x,
    const float* __restrict__ Wpsi,
    float* __restrict__ sArr, float* __restrict__ sstat,
    int ngroups, float inv_n)
{
  __shared__ float pAg[64], pAx[64], pK[64], pW[64];
  const int tid = threadIdx.x;
  if (tid < 64) {
    const float mG = stats[tid]*inv_n,       vG = stats[64 + tid]*inv_n  - mG*mG;
    const float mX = stats[128 + tid]*inv_n, vX = stats[192 + tid]*inv_n - mX*mX;
    const float Ag = gamma_g[tid] * rsqrtf(vG + BN_EPSF);
    const float Ax = gamma_x[tid] * rsqrtf(vX + BN_EPSF);
    pAg[tid] = Ag; pAx[tid] = Ax;
    pK[tid]  = beta_g[tid] - mG*Ag + beta_x[tid] - mX*Ax;
    pW[tid]  = Wpsi[tid];
  }
  __syncthreads();

  const int lane = tid & 63, wid = tid >> 6;
  const int row16 = lane & 15, quad = lane >> 4;
  float Ag[4], Ax[4], K[4], W[4];
#pragma unroll
  for (int cb = 0; cb < 4; ++cb) {
    const int c = cb*16 + row16;
    Ag[cb] = pAg[c]; Ax[cb] = pAx[c]; K[cb] = pK[c]; W[cb] = pW[c];
  }

  float aS = 0.f, aS2 = 0.f;
  const int g0 = blockIdx.x*4 + wid, ng = gridDim.x*4;
  for (int g = g0; g < ngroups; g += ng) {
    const char* base = (const char*)gx + (size_t)g*4096 + lane*32;
    const bf16x8 gA = *(const bf16x8*)(base);
    const bf16x8 gB = *(const bf16x8*)(base + 16);
    const bf16x8 xA = *(const bf16x8*)(base + 2048);
    const bf16x8 xB = *(const bf16x8*)(base + 2048 + 16);
    float ps[4] = {0,0,0,0};
#pragma unroll
    for (int cb = 0; cb < 4; ++cb) {
#pragma unroll
      for (int j = 0; j < 4; ++j) {
        const float gv = (float)(cb < 2 ? gA[cb*4 + j] : gB[(cb-2)*4 + j]);
        const float xv = (float)(cb < 2 ? xA[cb*4 + j] : xB[(cb-2)*4 + j]);
        float z = fmaf(gv, Ag[cb], fmaf(xv, Ax[cb], K[cb]));
        z = fmaxf(z, 0.f);
        ps[j] = fmaf(z, W[cb], ps[j]);
      }
    }
#pragma unroll
    for (int j = 0; j < 4; ++j) {
      ps[j] += __shfl_xor(ps[j], 1, 64);
      ps[j] += __shfl_xor(ps[j], 2, 64);
      ps[j] += __shfl_xor(ps[j], 4, 64);
      ps[j] += __shfl_xor(ps[j], 8, 64);
    }
    if (row16 == 0) {
#pragma unroll
      for (int j = 0; j < 4; ++j) {
        const float sv = ps[j];
        sArr[g*16 + quad*4 + j] = sv;
        aS += sv; aS2 += sv*sv;
      }
    }
  }
  aS  += __shfl_xor(aS, 16, 64);  aS  += __shfl_xor(aS, 32, 64);
  aS2 += __shfl_xor(aS2,16, 64);  aS2 += __shfl_xor(aS2,32, 64);
  if (lane == 0) { atomicAdd(&sstat[0], aS); atomicAdd(&sstat[1], aS2); }
}

// PHASE 2: out = skip * sigmoid(BN(s))  (bpsi cancels in BN)
__global__ void k_out(const float* __restrict__ skip,
                      const float* __restrict__ sArr,
                      const float* __restrict__ sstat,
                      const float* __restrict__ gamma_psi,
                      const float* __restrict__ beta_psi,
                      float* __restrict__ out, int N)
{
  const float inv_n = 1.0f / (float)N;
  const float m = sstat[0] * inv_n;
  const float v = sstat[1] * inv_n - m*m;
  const float A = gamma_psi[0] * rsqrtf(v + BN_EPSF);
  const float B = beta_psi[0] - m*A;
  const long total  = (long)N * (F_IN/4);
  const long stride = (long)gridDim.x * blockDim.x;
  for (long i = (long)blockIdx.x*blockDim.x + threadIdx.x; i < total; i += stride) {
    const int p = (int)(i >> 5);        // 32 f32x4 per point
    const float t = sArr[p]*A + B;
    const float psi = 1.0f / (1.0f + __expf(-t));
    f32x4 vv = ((const f32x4*)skip)[i];
    ((f32x4*)out)[i] = vv * psi;
  }
}

extern "C" void kernel_launch(void* const* d_in, const int* in_sizes, int n_in,
                              void* d_out, int out_size, void* d_ws, size_t ws_size,
                              hipStream_t stream)
{
  const float* gate      = (const float*)d_in[0];
  const float* skip      = (const float*)d_in[1];
  const float* Wg        = (const float*)d_in[2];
  const float* gamma_g   = (const float*)d_in[4];
  const float* beta_g    = (const float*)d_in[5];
  const float* Wx        = (const float*)d_in[6];
  const float* gamma_x   = (const float*)d_in[8];
  const float* beta_x    = (const float*)d_in[9];
  const float* Wpsi      = (const float*)d_in[10];
  const float* gamma_psi = (const float*)d_in[12];
  const float* beta_psi  = (const float*)d_in[13];

  float* ws   = (float*)d_ws;
  float* sArr = ws + 512;
  float* out  = (float*)d_out;

  const int N = in_sizes[0] / F_IN;
  const int ngroups = N / 16;

  // gx scratch: prefer d_ws (de-alias from out); fall back to d_out.
  const size_t gx_off   = 32u * 1024u * 1024u;
  const size_t gx_bytes = (size_t)ngroups * 4096u;
  bf16* gx = (ws_size >= gx_off + gx_bytes)
                 ? (bf16*)((char*)d_ws + gx_off)
                 : (bf16*)d_out;

  hipMemsetAsync(d_ws, 0, 512*sizeof(float), stream);

  k_p0<<<dim3(1024), dim3(512), 0, stream>>>(gate, skip, Wg, Wx, ws, gx, ngroups);
  k_p1<<<dim3(2048), dim3(256), 0, stream>>>(gx, ws, gamma_g, beta_g, gamma_x, beta_x,
                                             Wpsi, sArr, ws + 256, ngroups, 1.0f/(float)N);
  k_out<<<dim3(2048), dim3(256), 0, stream>>>(skip, sArr, ws + 256, gamma_psi, beta_psi, out, N);
}